// Round 14
// baseline (697.938 us; speedup 1.0000x reference)
//
#include <hip/hip_runtime.h>
#include <hip/hip_bf16.h>

typedef __hip_bfloat16 bf16;

__device__ __forceinline__ float ldf(const bf16* p)  { return __bfloat162float(*p); }
__device__ __forceinline__ float ldf(const float* p) { return *p; }
__device__ __forceinline__ void  stf(bf16* p, float v)  { *p = __float2bfloat16(v); }
__device__ __forceinline__ void  stf(float* p, float v) { *p = v; }
__device__ __forceinline__ bf16  f2b(float v) { return __float2bfloat16(v); }

// 2x bf16 MAC into f32 acc: acc += a.lo*b.lo + a.hi*b.hi   (VOP3P)
#define DOT2(acc, a, b) asm("v_dot2_f32_bf16 %0, %1, %2, %0" : "+v"(acc) : "v"(a), "v"(b))

__device__ __forceinline__ unsigned int pack2bf16(float a, float b) {
    bf16 ha = f2b(a), hb = f2b(b);
    unsigned short ua = *reinterpret_cast<unsigned short*>(&ha);
    unsigned short ub = *reinterpret_cast<unsigned short*>(&hb);
    return ((unsigned int)ub << 16) | (unsigned int)ua;
}

// unpack 8 bf16 (16B, aligned) -> 8 f32 (still used by nothing heavy)
__device__ __forceinline__ void ld_bf16x8(const bf16* p, float* x) {
    uint4 v = *reinterpret_cast<const uint4*>(p);
    x[0] = __uint_as_float(v.x << 16);
    x[1] = __uint_as_float(v.x & 0xffff0000u);
    x[2] = __uint_as_float(v.y << 16);
    x[3] = __uint_as_float(v.y & 0xffff0000u);
    x[4] = __uint_as_float(v.z << 16);
    x[5] = __uint_as_float(v.z & 0xffff0000u);
    x[6] = __uint_as_float(v.w << 16);
    x[7] = __uint_as_float(v.w & 0xffff0000u);
}

// ---------------------------------------------------------------------------
// conv1 specialized (unchanged): x (8,3,64,128,128) f32 -> z1 (8,4,32,64,64)
// ---------------------------------------------------------------------------
__global__ __launch_bounds__(256)
void conv1_k(const float* __restrict__ in, const float* __restrict__ w,
             const float* __restrict__ bias, float* __restrict__ out)
{
    constexpr int CIN = 3, COUT = 4, Din = 64, Hin = 128, Win = 128;
    constexpr int Dout = 32, Hout = 64, Wout = 64, HT = 4;
    __shared__ float sl[CIN * 4 * 4 * 16];
    __shared__ float sb[COUT];
    for (int i = threadIdx.x; i < CIN * 256; i += 256) {
        int co = i & 3, kw = (i >> 2) & 3, kh = (i >> 4) & 3;
        int kd = (i >> 6) & 3, ci = i >> 8;
        sl[i] = w[((co * CIN + ci) * 4 + kd) * 16 + kh * 4 + kw];
    }
    if (threadIdx.x < COUT) sb[threadIdx.x] = bias[threadIdx.x];
    __syncthreads();

    int idx = blockIdx.x * 256 + threadIdx.x;
    int ow = idx & 63; int t = idx >> 6;
    int ohb = t & 15;  t >>= 4;
    int od = t & 31;   int n = t >> 5;
    int oh0 = ohb * HT;
    int iwb = 2 * ow - 1;

    float acc[COUT][HT];
#pragma unroll
    for (int co = 0; co < COUT; co++) {
        float b = sb[co];
#pragma unroll
        for (int r = 0; r < HT; r++) acc[co][r] = b;
    }

    const float* inn = in + (long)n * CIN * Din * Hin * Win;

#pragma unroll
    for (int ci = 0; ci < CIN; ci++) {
#pragma unroll
        for (int kd = 0; kd < 4; kd++) {
            int id = 2 * od - 1 + kd;
            if ((unsigned)id >= (unsigned)Din) continue;
            const float* pl = inn + ((long)(ci * Din + id)) * (Hin * Win);
            float xr[10][4];
#pragma unroll
            for (int ihx = 0; ihx < 10; ihx++) {
                int ih = 2 * oh0 - 1 + ihx;
                bool okh = (unsigned)ih < (unsigned)Hin;
                const float* rw = pl + (long)ih * Win;
#pragma unroll
                for (int tap = 0; tap < 4; tap++) {
                    int iw = iwb + tap;
                    xr[ihx][tap] = (okh && (unsigned)iw < (unsigned)Win) ? rw[iw] : 0.0f;
                }
            }
#pragma unroll
            for (int kh = 0; kh < 4; kh++) {
                const float* wp = sl + ((ci * 4 + kd) * 4 + kh) * 16;
                float wr[4][4];
#pragma unroll
                for (int kw = 0; kw < 4; kw++)
                    *reinterpret_cast<float4*>(wr[kw]) =
                        *reinterpret_cast<const float4*>(wp + kw * 4);
#pragma unroll
                for (int r = 0; r < HT; r++) {
                    int ihx = 2 * r + kh;
#pragma unroll
                    for (int kw = 0; kw < 4; kw++) {
                        float xv = xr[ihx][kw];
#pragma unroll
                        for (int co = 0; co < COUT; co++)
                            acc[co][r] += xv * wr[kw][co];
                    }
                }
            }
        }
    }

#pragma unroll
    for (int co = 0; co < COUT; co++) {
        long base = ((long)(n * COUT + co) * Dout + od) * (Hout * Wout) + (long)oh0 * Wout + ow;
#pragma unroll
        for (int r = 0; r < HT; r++)
            out[base + (long)r * Wout] = fmaxf(acc[co][r], 0.0f);
    }
}

// ---------------------------------------------------------------------------
// Forward Conv3d generic (conv2, conv3).
// ---------------------------------------------------------------------------
template <int CIN, int COUT, int K, int STRIDE, int PAD, int WT, bool RELU,
          typename TIN, typename TOUT>
__global__ __launch_bounds__(256)
void convf_k(const TIN* __restrict__ in, const float* __restrict__ w,
             const float* __restrict__ bias, TOUT* __restrict__ out,
             int N, int Din, int Hin, int Win, int Dout, int Hout, int Wout)
{
    constexpr int WSZ = CIN * COUT * K * K * K;
    constexpr int IWN = (WT - 1) * STRIDE + K;
    __shared__ float sw[WSZ];
    __shared__ float sb[COUT];
    for (int i = threadIdx.x; i < WSZ; i += 256) sw[i] = w[i];
    for (int i = threadIdx.x; i < COUT; i += 256) sb[i] = bias[i];
    __syncthreads();

    int strips = Wout / WT;
    int idx = blockIdx.x * 256 + threadIdx.x;
    if (idx >= N * Dout * Hout * strips) return;
    int t = idx;
    int wsI = t % strips; t /= strips;
    int oh  = t % Hout;   t /= Hout;
    int od  = t % Dout;   int n = t / Dout;
    int ow0 = wsI * WT;
    int iw0 = ow0 * STRIDE - PAD;

    float acc[COUT][WT];
#pragma unroll
    for (int co = 0; co < COUT; co++)
#pragma unroll
        for (int j = 0; j < WT; j++) acc[co][j] = sb[co];

    const TIN* inn = in + (long)n * CIN * Din * Hin * Win;

#pragma unroll
    for (int ci = 0; ci < CIN; ci++) {
        const TIN* inc = inn + (long)ci * Din * Hin * Win;
#pragma unroll
        for (int kd = 0; kd < K; kd++) {
            int id = od * STRIDE - PAD + kd;
            if ((unsigned)id >= (unsigned)Din) continue;
#pragma unroll
            for (int kh = 0; kh < K; kh++) {
                int ih = oh * STRIDE - PAD + kh;
                if ((unsigned)ih >= (unsigned)Hin) continue;
                const TIN* row = inc + ((long)id * Hin + ih) * Win;
                float v[IWN];
#pragma unroll
                for (int q = 0; q < IWN; q++) {
                    int iw = iw0 + q;
                    v[q] = ((unsigned)iw < (unsigned)Win) ? ldf(row + iw) : 0.0f;
                }
#pragma unroll
                for (int kw = 0; kw < K; kw++) {
                    float wr[COUT];
#pragma unroll
                    for (int co = 0; co < COUT; co++)
                        wr[co] = sw[(((co * CIN + ci) * K + kd) * K + kh) * K + kw];
#pragma unroll
                    for (int j = 0; j < WT; j++) {
                        float xv = v[j * STRIDE + kw];
#pragma unroll
                        for (int co = 0; co < COUT; co++)
                            acc[co][j] += xv * wr[co];
                    }
                }
            }
        }
    }

    long obase = (((long)n * COUT) * Dout + od) * Hout * Wout + (long)oh * Wout + ow0;
#pragma unroll
    for (int co = 0; co < COUT; co++)
#pragma unroll
        for (int j = 0; j < WT; j++) {
            float r = acc[co][j];
            if (RELU) r = fmaxf(r, 0.0f);
            stf(&out[obase + (long)co * Dout * Hout * Wout + j], r);
        }
}

// ---------------------------------------------------------------------------
// prep_u: U[m][tap][co] for dec1 (unchanged).
// ---------------------------------------------------------------------------
__global__ __launch_bounds__(256)
void prep_u_k(const float* __restrict__ emb, const float* __restrict__ w,
              float* __restrict__ u_tab)
{
    constexpr int RS = 516;
    int i = blockIdx.x * 256 + threadIdx.x;
    if (i >= 33 * RS) return;
    int m = i / RS, r = i % RS;
    float val = 0.0f;
    if (m < 32 && r < 512) {
        int tap = r >> 3, co = r & 7;
        int kd = tap >> 4, kh = (tap >> 2) & 3, kw = tap & 3;
#pragma unroll
        for (int ci = 0; ci < 16; ci++)
            val += emb[m * 16 + ci] * w[((ci * 8 + co) << 6) + (kd << 4) + (kh << 2) + kw];
    }
    u_tab[i] = val;
}

// ---------------------------------------------------------------------------
// dec1 via U-table (unchanged).
// ---------------------------------------------------------------------------
__global__ __launch_bounds__(256)
void dect1_k(const unsigned int* __restrict__ codes,
             const float* __restrict__ u_tab,
             const float* __restrict__ bias, bf16* __restrict__ out)
{
    constexpr int Din = 16, Hin = 32, Win = 32;
    constexpr int Dout = 32, Hout = 64, Wout = 64, HT = 4, RS = 516;
    __shared__ float ut[33 * RS];
    __shared__ float sb[8];
    for (int i = threadIdx.x; i < 33 * RS; i += 256) ut[i] = u_tab[i];
    if (threadIdx.x < 8) sb[threadIdx.x] = bias[threadIdx.x];
    __syncthreads();

    int idx = blockIdx.x * 256 + threadIdx.x;
    int ow = idx & 63; int t = idx >> 6;
    int ohb = t & 15;  t >>= 4;
    int od = t & 31;   int n = t >> 5;

    int odd_w = ow & 1;
    int iwA = ow >> 1;
    int iwB = iwA + (odd_w ? 1 : -1);
    int kwA = odd_w ? 2 : 1, kwB = odd_w ? 0 : 3;
    bool okB = (unsigned)iwB < (unsigned)Win;

    int m_d = od >> 1, odd_d = od & 1;
    int idv[2], kdv[2];
    idv[0] = m_d;                    kdv[0] = odd_d ? 2 : 1;
    idv[1] = m_d + (odd_d ? 1 : -1); kdv[1] = odd_d ? 0 : 3;

    unsigned int c[2][4][2];
#pragma unroll
    for (int td = 0; td < 2; td++) {
        int id = idv[td];
        bool okd = (unsigned)id < (unsigned)Din;
        const unsigned int* cp = codes + ((long)(n * Din + (okd ? id : 0)) * Hin) * Win;
#pragma unroll
        for (int ihx = 0; ihx < 4; ihx++) {
            int ih = 2 * ohb - 1 + ihx;
            bool okh = okd && (unsigned)ih < (unsigned)Hin;
            c[td][ihx][0] = okh ? cp[ih * Win + iwA] : 32u;
            c[td][ihx][1] = (okh && okB) ? cp[ih * Win + iwB] : 32u;
        }
    }

    float acc[8][HT];
#pragma unroll
    for (int co = 0; co < 8; co++) {
        float b = sb[co];
#pragma unroll
        for (int r = 0; r < HT; r++) acc[co][r] = b;
    }

#pragma unroll
    for (int td = 0; td < 2; td++) {
        int kd = kdv[td];
#pragma unroll
        for (int p = 0; p < 2; p++) {
#pragma unroll
            for (int th = 0; th < 2; th++) {
                int kh = th ? (p ? 0 : 3) : (p ? 2 : 1);
                int offA = ((kd * 4 + kh) * 4 + kwA) * 8;
                int offB = ((kd * 4 + kh) * 4 + kwB) * 8;
#pragma unroll
                for (int j = 0; j < 2; j++) {
                    int r = 2 * j + p;
                    int ihx = 1 + j + (th ? (p ? 1 : -1) : 0);
                    const float* ua = ut + c[td][ihx][0] * RS + offA;
                    const float* ub = ut + c[td][ihx][1] * RS + offB;
                    float4 a0 = *reinterpret_cast<const float4*>(ua);
                    float4 a1 = *reinterpret_cast<const float4*>(ua + 4);
                    float4 b0 = *reinterpret_cast<const float4*>(ub);
                    float4 b1 = *reinterpret_cast<const float4*>(ub + 4);
                    acc[0][r] += a0.x + b0.x; acc[1][r] += a0.y + b0.y;
                    acc[2][r] += a0.z + b0.z; acc[3][r] += a0.w + b0.w;
                    acc[4][r] += a1.x + b1.x; acc[5][r] += a1.y + b1.y;
                    acc[6][r] += a1.z + b1.z; acc[7][r] += a1.w + b1.w;
                }
            }
        }
    }

    long pos0 = ((long)(n * Dout + od) * Hout + ohb * HT) * Wout + ow;
#pragma unroll
    for (int r = 0; r < HT; r++) {
        bf16 tmp[8];
#pragma unroll
        for (int co = 0; co < 8; co++) tmp[co] = f2b(fmaxf(acc[co][r], 0.0f));
        *reinterpret_cast<uint4*>(out + (pos0 + (long)r * Wout) * 8) =
            *reinterpret_cast<uint4*>(tmp);
    }
}

// ---------------------------------------------------------------------------
// dec2 via v_dot2_f32_bf16: weights pre-packed bf16 ci-pairs in LDS; x rows
// consumed as raw uint4 (4 ci-pairs), zero unpack. Structure = R13 (HT=4).
// wlu layout: [(kd*4+kh)*64 + kw*16 + co*4 + pr], pr = ci-pair index.
// ---------------------------------------------------------------------------
__global__ __launch_bounds__(256)
void dect2_k(const bf16* __restrict__ in, const float* __restrict__ w,
             const float* __restrict__ bias, bf16* __restrict__ out)
{
    constexpr int CIN = 8, COUT = 4, Din = 32, Hin = 64, Win = 64;
    constexpr int Dout = 64, Hout = 128, Wout = 128, HT = 4;
    __shared__ unsigned int wlu[1024];
    for (int i = threadIdx.x; i < 1024; i += 256) {
        int pr = i & 3, co = (i >> 2) & 3, kw = (i >> 4) & 3;
        int kh = (i >> 6) & 3, kd = (i >> 8) & 3;
        int ci0 = 2 * pr;
        float w0 = w[(((ci0)     * COUT + co) << 6) + (kd << 4) + (kh << 2) + kw];
        float w1 = w[(((ci0 + 1) * COUT + co) << 6) + (kd << 4) + (kh << 2) + kw];
        wlu[i] = pack2bf16(w0, w1);
    }
    __syncthreads();

    int idx = blockIdx.x * 256 + threadIdx.x;
    int ow = idx & 127; int t = idx >> 7;
    int ohb = t & 31;   t >>= 5;
    int od = t & 63;    int n = t >> 6;

    int odd_w = ow & 1;
    int iwA = ow >> 1;
    int iwB = iwA + (odd_w ? 1 : -1);
    int kwA = odd_w ? 2 : 1, kwB = odd_w ? 0 : 3;
    bool okBw = (unsigned)iwB < (unsigned)Win;

    float acc[COUT][HT]; // r = 2j+p
#pragma unroll
    for (int co = 0; co < COUT; co++) {
        float b = bias[co];
#pragma unroll
        for (int r = 0; r < HT; r++) acc[co][r] = b;
    }

    int m_d = od >> 1, odd_d = od & 1;

#pragma unroll 1
    for (int td = 0; td < 2; td++) {
        int id = (td == 0) ? m_d : m_d + (odd_d ? 1 : -1);
        if ((unsigned)id >= (unsigned)Din) continue;
        int kd = (td == 0) ? (odd_d ? 2 : 1) : (odd_d ? 0 : 3);
        const bf16* plane = in + ((long)(n * Din + id) * Hin) * (Win * CIN);
#pragma unroll 1
        for (int p = 0; p < 2; p++) {
#pragma unroll 1
            for (int th = 0; th < 2; th++) {
                int kh = (th == 0) ? (p ? 2 : 1) : (p ? 0 : 3);
                const unsigned int* wkh = wlu + ((kd * 4 + kh) << 6);
                uint4 wA[COUT], wB[COUT];
#pragma unroll
                for (int co = 0; co < COUT; co++) {
                    wA[co] = *reinterpret_cast<const uint4*>(wkh + kwA * 16 + co * 4);
                    wB[co] = *reinterpret_cast<const uint4*>(wkh + kwB * 16 + co * 4);
                }
#pragma unroll
                for (int j = 0; j < 2; j++) {
                    int m_h = ohb * 2 + j;
                    int ih = (th == 0) ? m_h : m_h + (p ? 1 : -1);
                    if ((unsigned)ih >= (unsigned)Hin) continue;
                    int r = 2 * j + p;
                    const bf16* rowb = plane + (long)ih * (Win * CIN);
                    uint4 xA = *reinterpret_cast<const uint4*>(rowb + iwA * CIN);
                    uint4 xB;
                    if (okBw) {
                        xB = *reinterpret_cast<const uint4*>(rowb + iwB * CIN);
                    } else {
                        xB.x = xB.y = xB.z = xB.w = 0u;
                    }
#pragma unroll
                    for (int co = 0; co < COUT; co++) {
                        DOT2(acc[co][r], xA.x, wA[co].x);
                        DOT2(acc[co][r], xA.y, wA[co].y);
                        DOT2(acc[co][r], xA.z, wA[co].z);
                        DOT2(acc[co][r], xA.w, wA[co].w);
                        DOT2(acc[co][r], xB.x, wB[co].x);
                        DOT2(acc[co][r], xB.y, wB[co].y);
                        DOT2(acc[co][r], xB.z, wB[co].z);
                        DOT2(acc[co][r], xB.w, wB[co].w);
                    }
                }
            }
        }
    }

    long pos0 = ((long)(n * Dout + od) * Hout + ohb * HT) * Wout + ow;
#pragma unroll
    for (int r = 0; r < HT; r++) {
        bf16 tmp[4];
#pragma unroll
        for (int co = 0; co < COUT; co++) tmp[co] = f2b(fmaxf(acc[co][r], 0.0f));
        *reinterpret_cast<uint2*>(out + (pos0 + (long)r * Wout) * COUT) =
            *reinterpret_cast<uint2*>(tmp);
    }
}

// ---------------------------------------------------------------------------
// dec3 via v_dot2_f32_bf16: x as raw uint2 (2 ci-pairs), weights packed in
// LDS. wlu layout: [(kd*3+kh)*18 + (kw*3+co)*2 + half], half = ci-pair.
// Structure = R13 scalar version (HT=4).
// ---------------------------------------------------------------------------
__global__ __launch_bounds__(256)
void dect3_k(const bf16* __restrict__ in, const float* __restrict__ w,
             const float* __restrict__ bias, float* __restrict__ out)
{
    constexpr int CIN = 4, COUT = 3, D = 64, H = 128, W = 128, HT = 4;
    __shared__ unsigned int wlu[9 * 18];
    for (int i = threadIdx.x; i < 162; i += 256) {
        int g = i / 18, rem = i % 18;
        int kwco = rem >> 1, half = rem & 1;
        int kw = kwco / 3, co = kwco % 3;
        int kd = g / 3, kh = g % 3;
        int ci0 = 2 * half;
        float w0 = w[((((ci0)     * COUT + co) * 3 + kd) * 3 + kh) * 3 + kw];
        float w1 = w[((((ci0 + 1) * COUT + co) * 3 + kd) * 3 + kh) * 3 + kw];
        wlu[i] = pack2bf16(w0, w1);
    }
    __syncthreads();

    int idx = blockIdx.x * 256 + threadIdx.x;
    int ow = idx & 127; int t = idx >> 7;
    int ohb = t & 31;   t >>= 5;
    int od = t & 63;    int n = t >> 6;

    float acc[COUT][HT];
#pragma unroll
    for (int co = 0; co < COUT; co++) {
        float b = bias[co];
#pragma unroll
        for (int r = 0; r < HT; r++) acc[co][r] = b;
    }

#pragma unroll 1
    for (int kd = 0; kd < 3; kd++) {
        int id = od + 1 - kd;
        if ((unsigned)id >= (unsigned)D) continue;
        const bf16* plane = in + ((long)(n * D + id) * H) * (W * CIN);
#pragma unroll 1
        for (int kh = 0; kh < 3; kh++) {
            uint2 wp[9]; // [(kw*3+co)] = {pair01, pair23}
#pragma unroll
            for (int i = 0; i < 9; i++)
                wp[i] = *reinterpret_cast<const uint2*>(wlu + (kd * 3 + kh) * 18 + i * 2);
#pragma unroll
            for (int r = 0; r < HT; r++) {
                int oh = ohb * HT + r;
                int ih = oh + 1 - kh;
                if ((unsigned)ih >= (unsigned)H) continue;
                const bf16* rowb = plane + (long)ih * (W * CIN);
                uint2 xs[3];
#pragma unroll
                for (int s = 0; s < 3; s++) {
                    int iw = ow - 1 + s;
                    if ((unsigned)iw < (unsigned)W) {
                        xs[s] = *reinterpret_cast<const uint2*>(rowb + iw * CIN);
                    } else {
                        xs[s].x = 0u; xs[s].y = 0u;
                    }
                }
#pragma unroll
                for (int kw = 0; kw < 3; kw++) {
                    uint2 xv = xs[2 - kw];
#pragma unroll
                    for (int co = 0; co < COUT; co++) {
                        uint2 w2 = wp[kw * 3 + co];
                        DOT2(acc[co][r], xv.x, w2.x);
                        DOT2(acc[co][r], xv.y, w2.y);
                    }
                }
            }
        }
    }

#pragma unroll
    for (int co = 0; co < COUT; co++) {
        long base = ((long)(n * COUT + co) * D + od) * H * W + (long)(ohb * HT) * W + ow;
#pragma unroll
        for (int r = 0; r < HT; r++) out[base + (long)r * W] = acc[co][r];
    }
}

// ---------------------------------------------------------------------------
// VQ (unchanged): codes u32 + float, LDS histogram, partial SSE.
// ---------------------------------------------------------------------------
__global__ __launch_bounds__(256)
void vq_k(const float* __restrict__ z, const float* __restrict__ emb,
          unsigned int* __restrict__ codes_u32, float* __restrict__ codes_out,
          unsigned int* __restrict__ hist_part, float* __restrict__ partial,
          int B, int S)
{
    __shared__ float se[32 * 16];
    __shared__ unsigned int sh[32];
    for (int i = threadIdx.x; i < 32 * 16; i += blockDim.x) se[i] = emb[i];
    if (threadIdx.x < 32) sh[threadIdx.x] = 0u;
    __syncthreads();

    int t = blockIdx.x * 256 + threadIdx.x;
    int Ntot = B * S;
    float sse = 0.0f;
    if (t < Ntot) {
        int n = t / S, s = t % S;
        const float* zp = z + (long)n * (16 * S) + s;
        float zv[16];
#pragma unroll
        for (int c = 0; c < 16; c++) zv[c] = zp[(long)c * S];

        float best = 3.0e38f;
        int bi = 0;
#pragma unroll
        for (int m = 0; m < 32; m++) {
            float d = 0.0f;
#pragma unroll
            for (int c = 0; c < 16; c++) {
                float df = zv[c] - se[m * 16 + c];
                d += df * df;
            }
            if (d < best) { best = d; bi = m; }
        }

#pragma unroll
        for (int c = 0; c < 16; c++) {
            float df = se[bi * 16 + c] - zv[c];
            sse += df * df;
        }
        codes_u32[t] = (unsigned int)bi;
        codes_out[t] = (float)bi;
        atomicAdd(&sh[bi], 1u);
    }

    __shared__ float red[256];
    red[threadIdx.x] = sse;
    __syncthreads();
    for (int o = 128; o > 0; o >>= 1) {
        if (threadIdx.x < (unsigned)o) red[threadIdx.x] += red[threadIdx.x + o];
        __syncthreads();
    }
    if (threadIdx.x == 0) partial[blockIdx.x] = red[0];
    if (threadIdx.x < 32) hist_part[blockIdx.x * 32 + threadIdx.x] = sh[threadIdx.x];
}

__global__ __launch_bounds__(256)
void finalize_k(const float* __restrict__ partial, int nPartial,
                const unsigned int* __restrict__ hist_part, int nBlocks,
                const float* __restrict__ cluster_size,
                float* __restrict__ out_vq, float* __restrict__ out_perp,
                float* __restrict__ out_used,
                float invNelem, float invNpos)
{
    __shared__ float red[256];
    __shared__ unsigned int cnt[32];
    float s = 0.0f;
    for (int i = threadIdx.x; i < nPartial; i += 256) s += partial[i];
    red[threadIdx.x] = s;
    if (threadIdx.x < 32) {
        unsigned int c = 0;
        for (int b = 0; b < nBlocks; b++) c += hist_part[b * 32 + threadIdx.x];
        cnt[threadIdx.x] = c;
    }
    __syncthreads();
    for (int o = 128; o > 0; o >>= 1) {
        if (threadIdx.x < (unsigned)o) red[threadIdx.x] += red[threadIdx.x + o];
        __syncthreads();
    }
    if (threadIdx.x == 0) {
        *out_vq = red[0] * invNelem;
        float acc = 0.0f;
        for (int m = 0; m < 32; m++) {
            float p = (float)cnt[m] * invNpos;
            acc += p * logf(p + 1e-10f);
        }
        *out_perp = expf(-acc);
        int used = 0;
        for (int m = 0; m < 32; m++)
            if (cluster_size[m] > 1e-5f) used++;
        *out_used = (float)used / 32.0f;
    }
}

// ---------------------------------------------------------------------------
extern "C" void kernel_launch(void* const* d_in, const int* in_sizes, int n_in,
                              void* d_out, int out_size, void* d_ws, size_t ws_size,
                              hipStream_t stream)
{
    const float* x       = (const float*)d_in[0];
    const float* w_conv1 = (const float*)d_in[2];
    const float* b_conv1 = (const float*)d_in[3];
    const float* w_conv2 = (const float*)d_in[4];
    const float* b_conv2 = (const float*)d_in[5];
    const float* w_conv3 = (const float*)d_in[6];
    const float* b_conv3 = (const float*)d_in[7];
    const float* emb     = (const float*)d_in[8];
    const float* csize   = (const float*)d_in[9];
    const float* w_dec1  = (const float*)d_in[10];
    const float* b_dec1  = (const float*)d_in[11];
    const float* w_dec2  = (const float*)d_in[12];
    const float* b_dec2  = (const float*)d_in[13];
    const float* w_dec3  = (const float*)d_in[14];
    const float* b_dec3  = (const float*)d_in[15];

    char* ws = (char*)d_ws;
    float* z1 = (float*)(ws + 0);           // (8,4,32,64,64)    f32 NCDHW
    float* z2 = (float*)(ws + 16777216);    // (8,8,16,32,32)    f32 NCDHW
    float* z3 = (float*)(ws + 20971520);    // (8,16,16,32,32)   f32 NCDHW
    unsigned int* codes_u32 = (unsigned int*)(ws + 29360128);   // 131072 u32
    float* u_tab = (float*)(ws + 29884416); // 33*516 f32
    bf16*  y1 = (bf16*)(ws + 37748736);     // (8,32,64,64,8)    bf16 NHWC
    bf16*  y2 = (bf16*)(ws + 54525952);     // (8,64,128,128,4)  bf16 NHWC
    unsigned int* hist_part = (unsigned int*)(ws + 121634816);  // 512*32 u32
    float* partial          = (float*)(ws + 121700352);         // 512 f32

    float* out       = (float*)d_out;
    float* out_vq    = out + 25165824;
    float* out_codes = out + 25165825;
    float* out_perp  = out + 25296897;
    float* out_used  = out + 25296898;

    // U-table (tiny, independent)
    prep_u_k<<<67, 256, 0, stream>>>(emb, w_dec1, u_tab);

    // Encoder
    conv1_k<<<1024, 256, 0, stream>>>(x, w_conv1, b_conv1, z1);
    convf_k<4, 8, 4, 2, 1, 4, true, float, float>
        <<<128, 256, 0, stream>>>(z1, w_conv2, b_conv2, z2, 8, 32, 64, 64, 16, 32, 32);
    convf_k<8, 16, 3, 1, 1, 4, false, float, float>
        <<<128, 256, 0, stream>>>(z2, w_conv3, b_conv3, z3, 8, 16, 32, 32, 16, 32, 32);

    // VQ
    vq_k<<<512, 256, 0, stream>>>(z3, emb, codes_u32, out_codes, hist_part, partial, 8, 16384);

    // Decoder
    dect1_k<<<1024, 256, 0, stream>>>(codes_u32, u_tab, b_dec1, y1);
    dect2_k<<<8192, 256, 0, stream>>>(y1, w_dec2, b_dec2, y2);
    dect3_k<<<8192, 256, 0, stream>>>(y2, w_dec3, b_dec3, out);

    // Scalars
    finalize_k<<<1, 256, 0, stream>>>(partial, 512, hist_part, 512, csize,
                                      out_vq, out_perp, out_used,
                                      1.0f / 2097152.0f, 1.0f / 131072.0f);
}

// Round 15
// 605.714 us; speedup vs baseline: 1.1523x; 1.1523x over previous
//
#include <hip/hip_runtime.h>
#include <hip/hip_bf16.h>

typedef __hip_bfloat16 bf16;

__device__ __forceinline__ float ldf(const bf16* p)  { return __bfloat162float(*p); }
__device__ __forceinline__ float ldf(const float* p) { return *p; }
__device__ __forceinline__ void  stf(bf16* p, float v)  { *p = __float2bfloat16(v); }
__device__ __forceinline__ void  stf(float* p, float v) { *p = v; }
__device__ __forceinline__ bf16  f2b(float v) { return __float2bfloat16(v); }

// unpack 4 bf16 (8B, aligned) -> 4 f32
__device__ __forceinline__ void ld_bf16x4(const bf16* p, float* x) {
    uint2 v = *reinterpret_cast<const uint2*>(p);
    x[0] = __uint_as_float(v.x << 16);
    x[1] = __uint_as_float(v.x & 0xffff0000u);
    x[2] = __uint_as_float(v.y << 16);
    x[3] = __uint_as_float(v.y & 0xffff0000u);
}
// unpack 8 bf16 (16B, aligned) -> 8 f32
__device__ __forceinline__ void ld_bf16x8(const bf16* p, float* x) {
    uint4 v = *reinterpret_cast<const uint4*>(p);
    x[0] = __uint_as_float(v.x << 16);
    x[1] = __uint_as_float(v.x & 0xffff0000u);
    x[2] = __uint_as_float(v.y << 16);
    x[3] = __uint_as_float(v.y & 0xffff0000u);
    x[4] = __uint_as_float(v.z << 16);
    x[5] = __uint_as_float(v.z & 0xffff0000u);
    x[6] = __uint_as_float(v.w << 16);
    x[7] = __uint_as_float(v.w & 0xffff0000u);
}

// ---------------------------------------------------------------------------
// conv1 specialized: x (8,3,64,128,128) f32 -> z1 (8,4,32,64,64)
// ---------------------------------------------------------------------------
__global__ __launch_bounds__(256)
void conv1_k(const float* __restrict__ in, const float* __restrict__ w,
             const float* __restrict__ bias, float* __restrict__ out)
{
    constexpr int CIN = 3, COUT = 4, Din = 64, Hin = 128, Win = 128;
    constexpr int Dout = 32, Hout = 64, Wout = 64, HT = 4;
    __shared__ float sl[CIN * 4 * 4 * 16];
    __shared__ float sb[COUT];
    for (int i = threadIdx.x; i < CIN * 256; i += 256) {
        int co = i & 3, kw = (i >> 2) & 3, kh = (i >> 4) & 3;
        int kd = (i >> 6) & 3, ci = i >> 8;
        sl[i] = w[((co * CIN + ci) * 4 + kd) * 16 + kh * 4 + kw];
    }
    if (threadIdx.x < COUT) sb[threadIdx.x] = bias[threadIdx.x];
    __syncthreads();

    int idx = blockIdx.x * 256 + threadIdx.x;
    int ow = idx & 63; int t = idx >> 6;
    int ohb = t & 15;  t >>= 4;
    int od = t & 31;   int n = t >> 5;
    int oh0 = ohb * HT;
    int iwb = 2 * ow - 1;

    float acc[COUT][HT];
#pragma unroll
    for (int co = 0; co < COUT; co++) {
        float b = sb[co];
#pragma unroll
        for (int r = 0; r < HT; r++) acc[co][r] = b;
    }

    const float* inn = in + (long)n * CIN * Din * Hin * Win;

#pragma unroll
    for (int ci = 0; ci < CIN; ci++) {
#pragma unroll
        for (int kd = 0; kd < 4; kd++) {
            int id = 2 * od - 1 + kd;
            if ((unsigned)id >= (unsigned)Din) continue;
            const float* pl = inn + ((long)(ci * Din + id)) * (Hin * Win);
            float xr[10][4];
#pragma unroll
            for (int ihx = 0; ihx < 10; ihx++) {
                int ih = 2 * oh0 - 1 + ihx;
                bool okh = (unsigned)ih < (unsigned)Hin;
                const float* rw = pl + (long)ih * Win;
#pragma unroll
                for (int tap = 0; tap < 4; tap++) {
                    int iw = iwb + tap;
                    xr[ihx][tap] = (okh && (unsigned)iw < (unsigned)Win) ? rw[iw] : 0.0f;
                }
            }
#pragma unroll
            for (int kh = 0; kh < 4; kh++) {
                const float* wp = sl + ((ci * 4 + kd) * 4 + kh) * 16;
                float wr[4][4];
#pragma unroll
                for (int kw = 0; kw < 4; kw++)
                    *reinterpret_cast<float4*>(wr[kw]) =
                        *reinterpret_cast<const float4*>(wp + kw * 4);
#pragma unroll
                for (int r = 0; r < HT; r++) {
                    int ihx = 2 * r + kh;
#pragma unroll
                    for (int kw = 0; kw < 4; kw++) {
                        float xv = xr[ihx][kw];
#pragma unroll
                        for (int co = 0; co < COUT; co++)
                            acc[co][r] += xv * wr[kw][co];
                    }
                }
            }
        }
    }

#pragma unroll
    for (int co = 0; co < COUT; co++) {
        long base = ((long)(n * COUT + co) * Dout + od) * (Hout * Wout) + (long)oh0 * Wout + ow;
#pragma unroll
        for (int r = 0; r < HT; r++)
            out[base + (long)r * Wout] = fmaxf(acc[co][r], 0.0f);
    }
}

// ---------------------------------------------------------------------------
// Forward Conv3d generic (conv2, conv3).
// ---------------------------------------------------------------------------
template <int CIN, int COUT, int K, int STRIDE, int PAD, int WT, bool RELU,
          typename TIN, typename TOUT>
__global__ __launch_bounds__(256)
void convf_k(const TIN* __restrict__ in, const float* __restrict__ w,
             const float* __restrict__ bias, TOUT* __restrict__ out,
             int N, int Din, int Hin, int Win, int Dout, int Hout, int Wout)
{
    constexpr int WSZ = CIN * COUT * K * K * K;
    constexpr int IWN = (WT - 1) * STRIDE + K;
    __shared__ float sw[WSZ];
    __shared__ float sb[COUT];
    for (int i = threadIdx.x; i < WSZ; i += 256) sw[i] = w[i];
    for (int i = threadIdx.x; i < COUT; i += 256) sb[i] = bias[i];
    __syncthreads();

    int strips = Wout / WT;
    int idx = blockIdx.x * 256 + threadIdx.x;
    if (idx >= N * Dout * Hout * strips) return;
    int t = idx;
    int wsI = t % strips; t /= strips;
    int oh  = t % Hout;   t /= Hout;
    int od  = t % Dout;   int n = t / Dout;
    int ow0 = wsI * WT;
    int iw0 = ow0 * STRIDE - PAD;

    float acc[COUT][WT];
#pragma unroll
    for (int co = 0; co < COUT; co++)
#pragma unroll
        for (int j = 0; j < WT; j++) acc[co][j] = sb[co];

    const TIN* inn = in + (long)n * CIN * Din * Hin * Win;

#pragma unroll
    for (int ci = 0; ci < CIN; ci++) {
        const TIN* inc = inn + (long)ci * Din * Hin * Win;
#pragma unroll
        for (int kd = 0; kd < K; kd++) {
            int id = od * STRIDE - PAD + kd;
            if ((unsigned)id >= (unsigned)Din) continue;
#pragma unroll
            for (int kh = 0; kh < K; kh++) {
                int ih = oh * STRIDE - PAD + kh;
                if ((unsigned)ih >= (unsigned)Hin) continue;
                const TIN* row = inc + ((long)id * Hin + ih) * Win;
                float v[IWN];
#pragma unroll
                for (int q = 0; q < IWN; q++) {
                    int iw = iw0 + q;
                    v[q] = ((unsigned)iw < (unsigned)Win) ? ldf(row + iw) : 0.0f;
                }
#pragma unroll
                for (int kw = 0; kw < K; kw++) {
                    float wr[COUT];
#pragma unroll
                    for (int co = 0; co < COUT; co++)
                        wr[co] = sw[(((co * CIN + ci) * K + kd) * K + kh) * K + kw];
#pragma unroll
                    for (int j = 0; j < WT; j++) {
                        float xv = v[j * STRIDE + kw];
#pragma unroll
                        for (int co = 0; co < COUT; co++)
                            acc[co][j] += xv * wr[co];
                    }
                }
            }
        }
    }

    long obase = (((long)n * COUT) * Dout + od) * Hout * Wout + (long)oh * Wout + ow0;
#pragma unroll
    for (int co = 0; co < COUT; co++)
#pragma unroll
        for (int j = 0; j < WT; j++) {
            float r = acc[co][j];
            if (RELU) r = fmaxf(r, 0.0f);
            stf(&out[obase + (long)co * Dout * Hout * Wout + j], r);
        }
}

// ---------------------------------------------------------------------------
// prep_u: U[m][tap][co] for dec1.
// ---------------------------------------------------------------------------
__global__ __launch_bounds__(256)
void prep_u_k(const float* __restrict__ emb, const float* __restrict__ w,
              float* __restrict__ u_tab)
{
    constexpr int RS = 516;
    int i = blockIdx.x * 256 + threadIdx.x;
    if (i >= 33 * RS) return;
    int m = i / RS, r = i % RS;
    float val = 0.0f;
    if (m < 32 && r < 512) {
        int tap = r >> 3, co = r & 7;
        int kd = tap >> 4, kh = (tap >> 2) & 3, kw = tap & 3;
#pragma unroll
        for (int ci = 0; ci < 16; ci++)
            val += emb[m * 16 + ci] * w[((ci * 8 + co) << 6) + (kd << 4) + (kh << 2) + kw];
    }
    u_tab[i] = val;
}

// ---------------------------------------------------------------------------
// dec1 via U-table.
// ---------------------------------------------------------------------------
__global__ __launch_bounds__(256)
void dect1_k(const unsigned int* __restrict__ codes,
             const float* __restrict__ u_tab,
             const float* __restrict__ bias, bf16* __restrict__ out)
{
    constexpr int Din = 16, Hin = 32, Win = 32;
    constexpr int Dout = 32, Hout = 64, Wout = 64, HT = 4, RS = 516;
    __shared__ float ut[33 * RS];
    __shared__ float sb[8];
    for (int i = threadIdx.x; i < 33 * RS; i += 256) ut[i] = u_tab[i];
    if (threadIdx.x < 8) sb[threadIdx.x] = bias[threadIdx.x];
    __syncthreads();

    int idx = blockIdx.x * 256 + threadIdx.x;
    int ow = idx & 63; int t = idx >> 6;
    int ohb = t & 15;  t >>= 4;
    int od = t & 31;   int n = t >> 5;

    int odd_w = ow & 1;
    int iwA = ow >> 1;
    int iwB = iwA + (odd_w ? 1 : -1);
    int kwA = odd_w ? 2 : 1, kwB = odd_w ? 0 : 3;
    bool okB = (unsigned)iwB < (unsigned)Win;

    int m_d = od >> 1, odd_d = od & 1;
    int idv[2], kdv[2];
    idv[0] = m_d;                    kdv[0] = odd_d ? 2 : 1;
    idv[1] = m_d + (odd_d ? 1 : -1); kdv[1] = odd_d ? 0 : 3;

    unsigned int c[2][4][2];
#pragma unroll
    for (int td = 0; td < 2; td++) {
        int id = idv[td];
        bool okd = (unsigned)id < (unsigned)Din;
        const unsigned int* cp = codes + ((long)(n * Din + (okd ? id : 0)) * Hin) * Win;
#pragma unroll
        for (int ihx = 0; ihx < 4; ihx++) {
            int ih = 2 * ohb - 1 + ihx;
            bool okh = okd && (unsigned)ih < (unsigned)Hin;
            c[td][ihx][0] = okh ? cp[ih * Win + iwA] : 32u;
            c[td][ihx][1] = (okh && okB) ? cp[ih * Win + iwB] : 32u;
        }
    }

    float acc[8][HT];
#pragma unroll
    for (int co = 0; co < 8; co++) {
        float b = sb[co];
#pragma unroll
        for (int r = 0; r < HT; r++) acc[co][r] = b;
    }

#pragma unroll
    for (int td = 0; td < 2; td++) {
        int kd = kdv[td];
#pragma unroll
        for (int p = 0; p < 2; p++) {
#pragma unroll
            for (int th = 0; th < 2; th++) {
                int kh = th ? (p ? 0 : 3) : (p ? 2 : 1);
                int offA = ((kd * 4 + kh) * 4 + kwA) * 8;
                int offB = ((kd * 4 + kh) * 4 + kwB) * 8;
#pragma unroll
                for (int j = 0; j < 2; j++) {
                    int r = 2 * j + p;
                    int ihx = 1 + j + (th ? (p ? 1 : -1) : 0);
                    const float* ua = ut + c[td][ihx][0] * RS + offA;
                    const float* ub = ut + c[td][ihx][1] * RS + offB;
                    float4 a0 = *reinterpret_cast<const float4*>(ua);
                    float4 a1 = *reinterpret_cast<const float4*>(ua + 4);
                    float4 b0 = *reinterpret_cast<const float4*>(ub);
                    float4 b1 = *reinterpret_cast<const float4*>(ub + 4);
                    acc[0][r] += a0.x + b0.x; acc[1][r] += a0.y + b0.y;
                    acc[2][r] += a0.z + b0.z; acc[3][r] += a0.w + b0.w;
                    acc[4][r] += a1.x + b1.x; acc[5][r] += a1.y + b1.y;
                    acc[6][r] += a1.z + b1.z; acc[7][r] += a1.w + b1.w;
                }
            }
        }
    }

    long pos0 = ((long)(n * Dout + od) * Hout + ohb * HT) * Wout + ow;
#pragma unroll
    for (int r = 0; r < HT; r++) {
        bf16 tmp[8];
#pragma unroll
        for (int co = 0; co < 8; co++) tmp[co] = f2b(fmaxf(acc[co][r], 0.0f));
        *reinterpret_cast<uint4*>(out + (pos0 + (long)r * Wout) * 8) =
            *reinterpret_cast<uint4*>(tmp);
    }
}

// ---------------------------------------------------------------------------
// dec2: ConvT3d 8->4, K4 S2 P1, ReLU. Scalar acc, HT=4 (R13 known-good).
// ---------------------------------------------------------------------------
__global__ __launch_bounds__(256)
void dect2_k(const bf16* __restrict__ in, const float* __restrict__ w,
             const float* __restrict__ bias, bf16* __restrict__ out)
{
    constexpr int CIN = 8, COUT = 4, Din = 32, Hin = 64, Win = 64;
    constexpr int Dout = 64, Hout = 128, Wout = 128, HT = 4;
    __shared__ float wl[4 * 4 * CIN * 4 * COUT]; // [kd][kh][ci][kw][co]
    for (int i = threadIdx.x; i < 2048; i += 256) {
        int co = i & 3, kw = (i >> 2) & 3, ci = (i >> 4) & 7;
        int kh = (i >> 7) & 3, kd = (i >> 9) & 3;
        wl[i] = w[((ci * COUT + co) << 6) + (kd << 4) + (kh << 2) + kw];
    }
    __syncthreads();

    int idx = blockIdx.x * 256 + threadIdx.x;
    int ow = idx & 127; int t = idx >> 7;
    int ohb = t & 31;   t >>= 5;
    int od = t & 63;    int n = t >> 6;

    int odd_w = ow & 1;
    int iwA = ow >> 1;
    int iwB = iwA + (odd_w ? 1 : -1);
    int kwA = odd_w ? 2 : 1, kwB = odd_w ? 0 : 3;
    bool okBw = (unsigned)iwB < (unsigned)Win;

    float acc[COUT][HT]; // [co][r], r = 2j+p
#pragma unroll
    for (int co = 0; co < COUT; co++) {
        float b = bias[co];
#pragma unroll
        for (int r = 0; r < HT; r++) acc[co][r] = b;
    }

    int m_d = od >> 1, odd_d = od & 1;

#pragma unroll 1
    for (int td = 0; td < 2; td++) {
        int id = (td == 0) ? m_d : m_d + (odd_d ? 1 : -1);
        if ((unsigned)id >= (unsigned)Din) continue;
        int kd = (td == 0) ? (odd_d ? 2 : 1) : (odd_d ? 0 : 3);
        const bf16* plane = in + ((long)(n * Din + id) * Hin) * (Win * CIN);
#pragma unroll 1
        for (int p = 0; p < 2; p++) {
#pragma unroll 1
            for (int th = 0; th < 2; th++) {
                int kh = (th == 0) ? (p ? 2 : 1) : (p ? 0 : 3);
                const float* wkh = wl + (kd * 4 + kh) * (CIN * 16);
                float xA[2][8], xB[2][8];
#pragma unroll
                for (int j = 0; j < 2; j++) {
                    int m_h = ohb * 2 + j;
                    int ih = (th == 0) ? m_h : m_h + (p ? 1 : -1);
                    if ((unsigned)ih < (unsigned)Hin) {
                        const bf16* rowb = plane + (long)ih * (Win * CIN);
                        ld_bf16x8(rowb + iwA * CIN, xA[j]);
                        if (okBw) {
                            ld_bf16x8(rowb + iwB * CIN, xB[j]);
                        } else {
                            for (int c2 = 0; c2 < 8; c2++) xB[j][c2] = 0.0f;
                        }
                    } else {
                        for (int c2 = 0; c2 < 8; c2++) { xA[j][c2] = 0.0f; xB[j][c2] = 0.0f; }
                    }
                }
#pragma unroll
                for (int ci = 0; ci < CIN; ci++) {
                    float wa[4], wb[4];
                    *reinterpret_cast<float4*>(wa) =
                        *reinterpret_cast<const float4*>(wkh + (ci * 4 + kwA) * 4);
                    *reinterpret_cast<float4*>(wb) =
                        *reinterpret_cast<const float4*>(wkh + (ci * 4 + kwB) * 4);
#pragma unroll
                    for (int j = 0; j < 2; j++) {
                        int r = 2 * j + p;
#pragma unroll
                        for (int co = 0; co < COUT; co++)
                            acc[co][r] += xA[j][ci] * wa[co] + xB[j][ci] * wb[co];
                    }
                }
            }
        }
    }

    long pos0 = ((long)(n * Dout + od) * Hout + ohb * HT) * Wout + ow;
#pragma unroll
    for (int r = 0; r < HT; r++) {
        bf16 tmp[4];
#pragma unroll
        for (int co = 0; co < COUT; co++) tmp[co] = f2b(fmaxf(acc[co][r], 0.0f));
        *reinterpret_cast<uint2*>(out + (pos0 + (long)r * Wout) * COUT) =
            *reinterpret_cast<uint2*>(tmp);
    }
}

// ---------------------------------------------------------------------------
// dec3: ConvT3d 4->3, K3 S1 P1 (R13 scalar HT=4 — measured 188 us).
// ---------------------------------------------------------------------------
__global__ __launch_bounds__(256)
void dect3_k(const bf16* __restrict__ in, const float* __restrict__ w,
             const float* __restrict__ bias, float* __restrict__ out)
{
    constexpr int CIN = 4, COUT = 3, D = 64, H = 128, W = 128, HT = 4;
    __shared__ float wl[9 * 36];
    for (int i = threadIdx.x; i < 324; i += 256) {
        int g = i / 36, rem = i % 36;
        int kwci = rem / 3, co = rem % 3;
        int kw = kwci >> 2, ci = kwci & 3;
        int kd = g / 3, kh = g % 3;
        wl[i] = w[(((ci * COUT + co) * 3 + kd) * 3 + kh) * 3 + kw];
    }
    __syncthreads();

    int idx = blockIdx.x * 256 + threadIdx.x;
    int ow = idx & 127; int t = idx >> 7;
    int ohb = t & 31;   t >>= 5;
    int od = t & 63;    int n = t >> 6;

    float acc[COUT][HT];
#pragma unroll
    for (int co = 0; co < COUT; co++) {
        float b = bias[co];
#pragma unroll
        for (int r = 0; r < HT; r++) acc[co][r] = b;
    }

#pragma unroll 1
    for (int kd = 0; kd < 3; kd++) {
        int id = od + 1 - kd;
        if ((unsigned)id >= (unsigned)D) continue;
        const bf16* plane = in + ((long)(n * D + id) * H) * (W * CIN);
#pragma unroll 1
        for (int kh = 0; kh < 3; kh++) {
            float wreg[36];
#pragma unroll
            for (int v4 = 0; v4 < 9; v4++)
                *reinterpret_cast<float4*>(wreg + v4 * 4) =
                    *reinterpret_cast<const float4*>(wl + (kd * 3 + kh) * 36 + v4 * 4);
#pragma unroll
            for (int r = 0; r < HT; r++) {
                int oh = ohb * HT + r;
                int ih = oh + 1 - kh;
                if ((unsigned)ih >= (unsigned)H) continue;
                const bf16* rowb = plane + (long)ih * (W * CIN);
                float x[3][4];
#pragma unroll
                for (int s = 0; s < 3; s++) {
                    int iw = ow - 1 + s;
                    if ((unsigned)iw < (unsigned)W) {
                        ld_bf16x4(rowb + iw * CIN, x[s]);
                    } else {
                        x[s][0] = x[s][1] = x[s][2] = x[s][3] = 0.0f;
                    }
                }
#pragma unroll
                for (int ci = 0; ci < 4; ci++)
#pragma unroll
                    for (int kw = 0; kw < 3; kw++) {
                        float xv = x[2 - kw][ci];
#pragma unroll
                        for (int co = 0; co < COUT; co++)
                            acc[co][r] += xv * wreg[(kw * 4 + ci) * 3 + co];
                    }
            }
        }
    }

#pragma unroll
    for (int co = 0; co < COUT; co++) {
        long base = ((long)(n * COUT + co) * D + od) * H * W + (long)(ohb * HT) * W + ow;
#pragma unroll
        for (int r = 0; r < HT; r++) out[base + (long)r * W] = acc[co][r];
    }
}

// ---------------------------------------------------------------------------
// VQ: codes u32 + float, LDS histogram, partial SSE.
// ---------------------------------------------------------------------------
__global__ __launch_bounds__(256)
void vq_k(const float* __restrict__ z, const float* __restrict__ emb,
          unsigned int* __restrict__ codes_u32, float* __restrict__ codes_out,
          unsigned int* __restrict__ hist_part, float* __restrict__ partial,
          int B, int S)
{
    __shared__ float se[32 * 16];
    __shared__ unsigned int sh[32];
    for (int i = threadIdx.x; i < 32 * 16; i += blockDim.x) se[i] = emb[i];
    if (threadIdx.x < 32) sh[threadIdx.x] = 0u;
    __syncthreads();

    int t = blockIdx.x * 256 + threadIdx.x;
    int Ntot = B * S;
    float sse = 0.0f;
    if (t < Ntot) {
        int n = t / S, s = t % S;
        const float* zp = z + (long)n * (16 * S) + s;
        float zv[16];
#pragma unroll
        for (int c = 0; c < 16; c++) zv[c] = zp[(long)c * S];

        float best = 3.0e38f;
        int bi = 0;
#pragma unroll
        for (int m = 0; m < 32; m++) {
            float d = 0.0f;
#pragma unroll
            for (int c = 0; c < 16; c++) {
                float df = zv[c] - se[m * 16 + c];
                d += df * df;
            }
            if (d < best) { best = d; bi = m; }
        }

#pragma unroll
        for (int c = 0; c < 16; c++) {
            float df = se[bi * 16 + c] - zv[c];
            sse += df * df;
        }
        codes_u32[t] = (unsigned int)bi;
        codes_out[t] = (float)bi;
        atomicAdd(&sh[bi], 1u);
    }

    __shared__ float red[256];
    red[threadIdx.x] = sse;
    __syncthreads();
    for (int o = 128; o > 0; o >>= 1) {
        if (threadIdx.x < (unsigned)o) red[threadIdx.x] += red[threadIdx.x + o];
        __syncthreads();
    }
    if (threadIdx.x == 0) partial[blockIdx.x] = red[0];
    if (threadIdx.x < 32) hist_part[blockIdx.x * 32 + threadIdx.x] = sh[threadIdx.x];
}

__global__ __launch_bounds__(256)
void finalize_k(const float* __restrict__ partial, int nPartial,
                const unsigned int* __restrict__ hist_part, int nBlocks,
                const float* __restrict__ cluster_size,
                float* __restrict__ out_vq, float* __restrict__ out_perp,
                float* __restrict__ out_used,
                float invNelem, float invNpos)
{
    __shared__ float red[256];
    __shared__ unsigned int cnt[32];
    float s = 0.0f;
    for (int i = threadIdx.x; i < nPartial; i += 256) s += partial[i];
    red[threadIdx.x] = s;
    if (threadIdx.x < 32) {
        unsigned int c = 0;
        for (int b = 0; b < nBlocks; b++) c += hist_part[b * 32 + threadIdx.x];
        cnt[threadIdx.x] = c;
    }
    __syncthreads();
    for (int o = 128; o > 0; o >>= 1) {
        if (threadIdx.x < (unsigned)o) red[threadIdx.x] += red[threadIdx.x + o];
        __syncthreads();
    }
    if (threadIdx.x == 0) {
        *out_vq = red[0] * invNelem;
        float acc = 0.0f;
        for (int m = 0; m < 32; m++) {
            float p = (float)cnt[m] * invNpos;
            acc += p * logf(p + 1e-10f);
        }
        *out_perp = expf(-acc);
        int used = 0;
        for (int m = 0; m < 32; m++)
            if (cluster_size[m] > 1e-5f) used++;
        *out_used = (float)used / 32.0f;
    }
}

// ---------------------------------------------------------------------------
extern "C" void kernel_launch(void* const* d_in, const int* in_sizes, int n_in,
                              void* d_out, int out_size, void* d_ws, size_t ws_size,
                              hipStream_t stream)
{
    const float* x       = (const float*)d_in[0];
    const float* w_conv1 = (const float*)d_in[2];
    const float* b_conv1 = (const float*)d_in[3];
    const float* w_conv2 = (const float*)d_in[4];
    const float* b_conv2 = (const float*)d_in[5];
    const float* w_conv3 = (const float*)d_in[6];
    const float* b_conv3 = (const float*)d_in[7];
    const float* emb     = (const float*)d_in[8];
    const float* csize   = (const float*)d_in[9];
    const float* w_dec1  = (const float*)d_in[10];
    const float* b_dec1  = (const float*)d_in[11];
    const float* w_dec2  = (const float*)d_in[12];
    const float* b_dec2  = (const float*)d_in[13];
    const float* w_dec3  = (const float*)d_in[14];
    const float* b_dec3  = (const float*)d_in[15];

    char* ws = (char*)d_ws;
    float* z1 = (float*)(ws + 0);           // (8,4,32,64,64)    f32 NCDHW
    float* z2 = (float*)(ws + 16777216);    // (8,8,16,32,32)    f32 NCDHW
    float* z3 = (float*)(ws + 20971520);    // (8,16,16,32,32)   f32 NCDHW
    unsigned int* codes_u32 = (unsigned int*)(ws + 29360128);   // 131072 u32
    float* u_tab = (float*)(ws + 29884416); // 33*516 f32
    bf16*  y1 = (bf16*)(ws + 37748736);     // (8,32,64,64,8)    bf16 NHWC
    bf16*  y2 = (bf16*)(ws + 54525952);     // (8,64,128,128,4)  bf16 NHWC
    unsigned int* hist_part = (unsigned int*)(ws + 121634816);  // 512*32 u32
    float* partial          = (float*)(ws + 121700352);         // 512 f32

    float* out       = (float*)d_out;
    float* out_vq    = out + 25165824;
    float* out_codes = out + 25165825;
    float* out_perp  = out + 25296897;
    float* out_used  = out + 25296898;

    // U-table (tiny, independent)
    prep_u_k<<<67, 256, 0, stream>>>(emb, w_dec1, u_tab);

    // Encoder
    conv1_k<<<1024, 256, 0, stream>>>(x, w_conv1, b_conv1, z1);
    convf_k<4, 8, 4, 2, 1, 4, true, float, float>
        <<<128, 256, 0, stream>>>(z1, w_conv2, b_conv2, z2, 8, 32, 64, 64, 16, 32, 32);
    convf_k<8, 16, 3, 1, 1, 4, false, float, float>
        <<<128, 256, 0, stream>>>(z2, w_conv3, b_conv3, z3, 8, 16, 32, 32, 16, 32, 32);

    // VQ
    vq_k<<<512, 256, 0, stream>>>(z3, emb, codes_u32, out_codes, hist_part, partial, 8, 16384);

    // Decoder
    dect1_k<<<1024, 256, 0, stream>>>(codes_u32, u_tab, b_dec1, y1);
    dect2_k<<<8192, 256, 0, stream>>>(y1, w_dec2, b_dec2, y2);
    dect3_k<<<8192, 256, 0, stream>>>(y2, w_dec3, b_dec3, out);

    // Scalars
    finalize_k<<<1, 256, 0, stream>>>(partial, 512, hist_part, 512, csize,
                                      out_vq, out_perp, out_used,
                                      1.0f / 2097152.0f, 1.0f / 131072.0f);
}